// Round 2
// 487.854 us; speedup vs baseline: 1.0562x; 1.0562x over previous
//
#include <hip/hip_runtime.h>
#include <stdint.h>
#include <cmath>

typedef unsigned short u16;
typedef unsigned int u32;
typedef __attribute__((ext_vector_type(8))) __bf16 bf16x8;
typedef __attribute__((ext_vector_type(4))) float f32x4;

#define HIDDEN 4096
#define NH 32
#define NKV 8
#define HD 128
#define S_LEN 2048

__device__ __forceinline__ u16 f2bf(float f) {
    u32 x = __float_as_uint(f);
    x += 0x7fff + ((x >> 16) & 1);   // RNE
    return (u16)(x >> 16);
}
__device__ __forceinline__ float bf2f(u16 u) {
    return __uint_as_float(((u32)u) << 16);
}
__device__ __forceinline__ float fexp2(float x) {
#if __has_builtin(__builtin_amdgcn_exp2f)
    return __builtin_amdgcn_exp2f(x);
#else
    return __expf(x * 0.6931471805599453f);
#endif
}

// DPP rotate within 16-lane row (VALU pipe, not DS). row_ror:N = 0x120+N.
template <int N>
__device__ __forceinline__ float dpp_ror(float v) {
    int i = __builtin_amdgcn_update_dpp(0, __float_as_int(v),
                                        0x120 + N, 0xf, 0xf, true);
    return __int_as_float(i);
}
__device__ __forceinline__ float row_max16(float x) {
    x = fmaxf(x, dpp_ror<1>(x));
    x = fmaxf(x, dpp_ror<2>(x));
    x = fmaxf(x, dpp_ror<4>(x));
    x = fmaxf(x, dpp_ror<8>(x));
    return x;
}
__device__ __forceinline__ float row_sum16(float x) {
    x += dpp_ror<1>(x);
    x += dpp_ror<2>(x);
    x += dpp_ror<4>(x);
    x += dpp_ror<8>(x);
    return x;
}

typedef __attribute__((address_space(1))) const void gv_t;
typedef __attribute__((address_space(3))) void lv_t;
__device__ __forceinline__ void async16(const u16* g, u16* s) {
    __builtin_amdgcn_global_load_lds((gv_t*)g, (lv_t*)s, 16, 0, 0);
}

// ---------------- fused f32 -> bf16 convert (all 5 tensors, contiguous dst) ----------
#define F4_HS   2097152u
#define F4_WQ   4194304u
#define F4_WKV  1048576u
__global__ void cvt_all(const float* __restrict__ s0, const float* __restrict__ s1,
                        const float* __restrict__ s2, const float* __restrict__ s3,
                        const float* __restrict__ s4, u16* __restrict__ dst) {
    u32 i = blockIdx.x * 256 + threadIdx.x;   // < 12582912
    const float* src; u32 off;
    if (i < F4_HS)                              { src = s0; off = 0; }
    else if (i < F4_HS + F4_WQ)                 { src = s1; off = F4_HS; }
    else if (i < F4_HS + F4_WQ + F4_WKV)        { src = s2; off = F4_HS + F4_WQ; }
    else if (i < F4_HS + F4_WQ + 2 * F4_WKV)    { src = s3; off = F4_HS + F4_WQ + F4_WKV; }
    else                                        { src = s4; off = F4_HS + F4_WQ + 2 * F4_WKV; }
    float4 v = ((const float4*)src)[i - off];
    union { u16 u[4]; uint2 w; } pk;
    pk.u[0] = f2bf(v.x); pk.u[1] = f2bf(v.y);
    pk.u[2] = f2bf(v.z); pk.u[3] = f2bf(v.w);
    ((uint2*)dst)[i] = pk.w;
}

// ---------------- bf16 GEMM core: 128x128 tile, BK=64 ----------------
#define GEMM_PROLOGUE_AND_MAINLOOP(Aptr, Bptr, Kdim)                                   \
    __shared__ u16 sA[128 * 64];                                                       \
    __shared__ u16 sB[128 * 64];                                                       \
    const int tid = threadIdx.x;                                                       \
    const int w = tid >> 6, lane = tid & 63;                                           \
    const int l15 = lane & 15, quad = lane >> 4;                                       \
    const int m0 = blockIdx.y * 128, n0 = blockIdx.x * 128;                            \
    const int wm = w & 1, wn = w >> 1;                                                 \
    f32x4 acc[4][4];                                                                   \
    _Pragma("unroll") for (int mi = 0; mi < 4; ++mi)                                   \
    _Pragma("unroll") for (int ni = 0; ni < 4; ++ni)                                   \
    _Pragma("unroll") for (int r = 0; r < 4; ++r) acc[mi][ni][r] = 0.f;                \
    for (int kt = 0; kt < (Kdim); kt += 64) {                                          \
        _Pragma("unroll") for (int i = 0; i < 4; ++i) {                                \
            int c = (i * 4 + w) * 64 + lane;                                           \
            int r = c >> 3, sl = c & 7, g = sl ^ (r & 7);                              \
            async16((Aptr) + (size_t)(m0 + r) * (Kdim) + kt + g * 8, &sA[c * 8]);      \
        }                                                                              \
        _Pragma("unroll") for (int i = 0; i < 4; ++i) {                                \
            int c = (i * 4 + w) * 64 + lane;                                           \
            int r = c >> 3, sl = c & 7, g = sl ^ (r & 7);                              \
            async16((Bptr) + (size_t)(n0 + r) * (Kdim) + kt + g * 8, &sB[c * 8]);      \
        }                                                                              \
        __syncthreads();                                                               \
        _Pragma("unroll") for (int ks = 0; ks < 2; ++ks) {                             \
            bf16x8 af[4], bf[4];                                                       \
            _Pragma("unroll") for (int t = 0; t < 4; ++t) {                            \
                int row = wm * 64 + t * 16 + l15;                                      \
                int sl = (ks * 4 + quad) ^ (row & 7);                                  \
                af[t] = *(const bf16x8*)&sA[row * 64 + sl * 8];                        \
            }                                                                          \
            _Pragma("unroll") for (int t = 0; t < 4; ++t) {                            \
                int row = wn * 64 + t * 16 + l15;                                      \
                int sl = (ks * 4 + quad) ^ (row & 7);                                  \
                bf[t] = *(const bf16x8*)&sB[row * 64 + sl * 8];                        \
            }                                                                          \
            _Pragma("unroll") for (int mi = 0; mi < 4; ++mi)                           \
            _Pragma("unroll") for (int ni = 0; ni < 4; ++ni)                           \
                acc[mi][ni] = __builtin_amdgcn_mfma_f32_16x16x32_bf16(                 \
                    af[mi], bf[ni], acc[mi][ni], 0, 0, 0);                             \
        }                                                                              \
        __syncthreads();                                                               \
    }

// Generic: C[M,N] = A[M,K] * B[N,K]^T, f32 out (O-projection)
__global__ __launch_bounds__(256, 2) void gemm_bt_f32(
    const u16* __restrict__ A, const u16* __restrict__ B, float* __restrict__ C,
    int N, int K)
{
    GEMM_PROLOGUE_AND_MAINLOOP(A, B, K)
#pragma unroll
    for (int mi = 0; mi < 4; ++mi) {
        int row = m0 + wm * 64 + mi * 16 + quad * 4;
#pragma unroll
        for (int ni = 0; ni < 4; ++ni) {
            int col = n0 + wn * 64 + ni * 16 + l15;
#pragma unroll
            for (int r = 0; r < 4; ++r)
                C[(size_t)(row + r) * N + col] = acc[mi][ni][r];
        }
    }
}

// Fused QKV: A=[2048,4096] hs, B=[6144,4096] (wq|wk|wv rows), routed output.
__global__ __launch_bounds__(256, 2) void gemm_qkv(
    const u16* __restrict__ A, const u16* __restrict__ B,
    u16* __restrict__ qb, u16* __restrict__ kbuf, u16* __restrict__ vt)
{
    GEMM_PROLOGUE_AND_MAINLOOP(A, B, HIDDEN)
    if (n0 < 4096 + 1024) {   // q or k path: row-major bf16
        u16* outp; int ldo, cb;
        if (n0 < 4096) { outp = qb; ldo = HIDDEN; cb = n0; }
        else           { outp = kbuf; ldo = NKV * HD; cb = n0 - 4096; }
#pragma unroll
        for (int mi = 0; mi < 4; ++mi) {
            int row = m0 + wm * 64 + mi * 16 + quad * 4;
#pragma unroll
            for (int ni = 0; ni < 4; ++ni) {
                int col = cb + wn * 64 + ni * 16 + l15;
#pragma unroll
                for (int r = 0; r < 4; ++r)
                    outp[(size_t)(row + r) * ldo + col] = f2bf(acc[mi][ni][r]);
            }
        }
    } else {                  // v path: transposed vt[c][s]
        int cb = n0 - (4096 + 1024);
#pragma unroll
        for (int mi = 0; mi < 4; ++mi) {
            int row = m0 + wm * 64 + mi * 16 + quad * 4;
#pragma unroll
            for (int ni = 0; ni < 4; ++ni) {
                int c = cb + wn * 64 + ni * 16 + l15;
                union { u16 u[4]; uint2 v; } pk;
#pragma unroll
                for (int r = 0; r < 4; ++r) pk.u[r] = f2bf(acc[mi][ni][r]);
                *(uint2*)&vt[(size_t)c * S_LEN + row] = pk.v;
            }
        }
    }
}

// ---------------- RoPE: f64 table precompute + bf16 apply ----------------
struct DTab { double f[64]; };
__global__ void rope_table(const int* __restrict__ pos, float2* __restrict__ tab,
                           DTab dt) {
    int idx = blockIdx.x * 256 + threadIdx.x;   // < 2048*64
    int d = idx & 63, s = idx >> 6;
    double fr = (double)pos[s] * dt.f[d];
    double sd, cd;
    sincos(fr, &sd, &cd);
    tab[idx] = make_float2((float)cd, (float)sd);
}

#define Q_ITEMS (S_LEN * NH * 64)    // 4194304
__global__ void rope_apply(u16* __restrict__ qb, u16* __restrict__ kb,
                           const float2* __restrict__ tab, float qscale) {
    int idx = blockIdx.x * 256 + threadIdx.x;
    u16* buf; int logH; float osc;
    if (idx < Q_ITEMS) { buf = qb; logH = 5; osc = qscale; }
    else { idx -= Q_ITEMS; buf = kb; logH = 3; osc = 1.0f; }
    int d = idx & 63;
    int rest = idx >> 6;            // = s*H + h
    int s = rest >> logH;
    float2 cs = tab[s * 64 + d];
    float c = cs.x * osc, sn = cs.y * osc;
    u16* p = buf + (size_t)rest * HD + d;
    float x1 = bf2f(p[0]), x2 = bf2f(p[64]);
    p[0]  = f2bf(x1 * c - x2 * sn);
    p[64] = f2bf(x2 * c + x1 * sn);
}

// ---------------- flash attention ----------------
// v3: q-tile 128 (4 waves, 256 thr), KBLK 64, grid 16x32=512 blocks.
//   LDS ~50KB -> 2 independent blocks/CU, so one block's barrier drains overlap
//   the other block's MFMA/VALU.
// + defer-rescale (T13): skip the 64-mult O rescale + alpha exp2 unless some
//   row max grew by >8 (exp2 domain => P bounded by 2^8; f32 accum is fine).
// (v2's v_cvt_pk_bf16_f32 asm reverted: unverifiable half-order semantics were
//  the prime suspect for the absmax-5.3 failure; hand-RNE f2bf is proven.)
// Pipeline: barrier A (sK reads done) -> issue stageK(next) -> PV -> barrier B
// (sV reads done) -> issue stageV(next).
__global__ __launch_bounds__(256, 2) void attn_kernel(
    const u16* __restrict__ Q, const u16* __restrict__ Kb,
    const u16* __restrict__ Vt, u16* __restrict__ O)
{
    __shared__ u16 sK[64 * 128];                     // 16 KB
    __shared__ u16 sV[128 * 64];                     // 16 KB
    __shared__ __align__(16) u16 sP[4][8 * 264];     // 16.5 KB, per-wave private
    __shared__ float sAl[4][32];

    const int tid = threadIdx.x;
    const int w = tid >> 6, lane = tid & 63;
    const int l15 = lane & 15, quad = lane >> 4;
    const int h = blockIdx.y, q0 = blockIdx.x * 128;
    const int hk = h >> 2;
    u16* const sPw = sP[w];

    // Q frags (A-operand: m=lane&15, k=quad*8+j); Q pre-scaled by sm_scale*log2e
    bf16x8 qf[2][4];
#pragma unroll
    for (int mt = 0; mt < 2; ++mt)
#pragma unroll
        for (int ks = 0; ks < 4; ++ks)
            qf[mt][ks] = *(const bf16x8*)(Q + (size_t)(q0 + w * 32 + mt * 16 + l15) * HIDDEN
                                           + h * HD + ks * 32 + quad * 8);

    f32x4 oc[8][2];
#pragma unroll
    for (int dt = 0; dt < 8; ++dt)
#pragma unroll
        for (int nt = 0; nt < 2; ++nt)
#pragma unroll
            for (int r = 0; r < 4; ++r) oc[dt][nt][r] = 0.f;
    float m_r[2][4], l_r[2][4];
#pragma unroll
    for (int mt = 0; mt < 2; ++mt)
#pragma unroll
        for (int r = 0; r < 4; ++r) { m_r[mt][r] = -1e30f; l_r[mt][r] = 0.f; }

    // staging: 1024 chunks of 16B per tile, 256 threads x 4; XOR swizzle.
    // k0 is the ELEMENT offset (kbi * 64).
    auto stageK = [&](int k0) {
#pragma unroll
        for (int i = 0; i < 4; ++i) {
            int c = i * 256 + tid;
            int r = c >> 4, sl = c & 15, g = sl ^ (r & 15);
            async16(Kb + (size_t)(k0 + r) * (NKV * HD) + hk * HD + g * 8, &sK[c * 8]);
        }
    };
    auto stageV = [&](int k0) {
#pragma unroll
        for (int i = 0; i < 4; ++i) {
            int c = i * 256 + tid;
            int r = c >> 3, sl = c & 7, g = sl ^ (r & 7);
            async16(Vt + (size_t)(hk * HD + r) * S_LEN + k0 + g * 8, &sV[c * 8]);
        }
    };

    stageK(0);
    stageV(0);
    __syncthreads();

    for (int kbi = 0; kbi < 32; ++kbi) {
        // ---- S = Q K^T from sK ----
        f32x4 sa[2][4];
#pragma unroll
        for (int mt = 0; mt < 2; ++mt)
#pragma unroll
            for (int nt = 0; nt < 4; ++nt)
#pragma unroll
                for (int r = 0; r < 4; ++r) sa[mt][nt][r] = 0.f;
#pragma unroll
        for (int ks = 0; ks < 4; ++ks) {
            bf16x8 kf[4];
#pragma unroll
            for (int nt = 0; nt < 4; ++nt) {
                int row = nt * 16 + l15;
                int sl = (ks * 4 + quad) ^ (row & 15);
                kf[nt] = *(const bf16x8*)&sK[row * 128 + sl * 8];
            }
#pragma unroll
            for (int mt = 0; mt < 2; ++mt)
#pragma unroll
                for (int nt = 0; nt < 4; ++nt)
                    sa[mt][nt] = __builtin_amdgcn_mfma_f32_16x16x32_bf16(
                        qf[mt][ks], kf[nt], sa[mt][nt], 0, 0, 0);
        }

        // ---- online softmax (DPP reductions, exp2 domain, deferred rescale) ----
        float mxv[2][4];
        bool grow = false;
#pragma unroll
        for (int mt = 0; mt < 2; ++mt)
#pragma unroll
            for (int r = 0; r < 4; ++r) {
                float mx = sa[mt][0][r];
#pragma unroll
                for (int nt = 1; nt < 4; ++nt) mx = fmaxf(mx, sa[mt][nt][r]);
                mx = row_max16(mx);
                mxv[mt][r] = mx;
                grow = grow || (mx > m_r[mt][r] + 8.f);
            }
        const int dorescale = __any((int)grow);   // wave-uniform
        if (dorescale) {
#pragma unroll
            for (int mt = 0; mt < 2; ++mt)
#pragma unroll
                for (int r = 0; r < 4; ++r) {
                    float mnew = fmaxf(m_r[mt][r], mxv[mt][r]);
                    float alpha = fexp2(m_r[mt][r] - mnew);
                    m_r[mt][r] = mnew;
                    l_r[mt][r] *= alpha;
                    if (l15 == 0) sAl[w][mt * 16 + quad * 4 + r] = alpha;
                }
        }
#pragma unroll
        for (int mt = 0; mt < 2; ++mt)
#pragma unroll
            for (int r = 0; r < 4; ++r) {
                int ql = mt * 16 + quad * 4 + r;
                // chunk-major P: (q,k) at (k>>3)*264 + q*8 + (k&7); k = nt*16+l15
                u16* pb = sPw + (l15 >> 3) * 264 + ql * 8 + (l15 & 7);
                float mm = m_r[mt][r];
                float rs = 0.f;
#pragma unroll
                for (int nt = 0; nt < 4; ++nt) {
                    float p = fexp2(sa[mt][nt][r] - mm);
                    rs += p;
                    pb[nt * 528] = f2bf(p);
                }
                rs = row_sum16(rs);
                l_r[mt][r] += rs;
            }

        __syncthreads();                    // A: all sK reads done; prior stageV drained
        if (kbi < 31) stageK((kbi + 1) * 64);

        // ---- rescale O^T acc (wave-local), only when the max actually grew ----
        if (dorescale) {
            float al0 = sAl[w][l15], al1 = sAl[w][16 + l15];
#pragma unroll
            for (int dt = 0; dt < 8; ++dt)
#pragma unroll
                for (int r = 0; r < 4; ++r) { oc[dt][0][r] *= al0; oc[dt][1][r] *= al1; }
        }

        // ---- O^T += V^T P^T from sV, sPw ----
#pragma unroll
        for (int ks = 0; ks < 2; ++ks) {
            bf16x8 vf[8], pf[2];
#pragma unroll
            for (int dt = 0; dt < 8; ++dt) {
                int row = dt * 16 + l15;
                int sl = (ks * 4 + quad) ^ (row & 7);
                vf[dt] = *(const bf16x8*)&sV[row * 64 + sl * 8];
            }
#pragma unroll
            for (int nt = 0; nt < 2; ++nt)
                pf[nt] = *(const bf16x8*)&sPw[(ks * 4 + quad) * 264 + (nt * 16 + l15) * 8];
#pragma unroll
            for (int dt = 0; dt < 8; ++dt)
#pragma unroll
                for (int nt = 0; nt < 2; ++nt)
                    oc[dt][nt] = __builtin_amdgcn_mfma_f32_16x16x32_bf16(
                        vf[dt], pf[nt], oc[dt][nt], 0, 0, 0);
        }

        __syncthreads();                    // B: all sV reads done; stageK drained
        if (kbi < 31) stageV((kbi + 1) * 64);
    }

    // ---- finalize: normalize, store O[q][h*128+d] bf16 ----
#pragma unroll
    for (int mt = 0; mt < 2; ++mt)
#pragma unroll
        for (int r = 0; r < 4; ++r)
            if (l15 == 0) sAl[w][mt * 16 + quad * 4 + r] = l_r[mt][r];
    float il[2];
    il[0] = 1.f / sAl[w][l15];
    il[1] = 1.f / sAl[w][16 + l15];
#pragma unroll
    for (int nt = 0; nt < 2; ++nt)
#pragma unroll
        for (int dt = 0; dt < 8; ++dt) {
            union { u16 u[4]; uint2 v; } pk;
#pragma unroll
            for (int r = 0; r < 4; ++r) pk.u[r] = f2bf(oc[dt][nt][r] * il[nt]);
            *(uint2*)(O + (size_t)(q0 + w * 32 + nt * 16 + l15) * HIDDEN
                        + h * HD + dt * 16 + quad * 4) = pk.v;
        }
}

// ---------------- host ----------------
extern "C" void kernel_launch(void* const* d_in, const int* in_sizes, int n_in,
                              void* d_out, int out_size, void* d_ws, size_t ws_size,
                              hipStream_t stream) {
    const float* hs = (const float*)d_in[0];
    const int* pos  = (const int*)d_in[1];
    const float* wq = (const float*)d_in[2];
    const float* wk = (const float*)d_in[3];
    const float* wv = (const float*)d_in[4];
    const float* wo = (const float*)d_in[5];
    float* out = (float*)d_out;

    u16* ws    = (u16*)d_ws;
    u16* hid16 = ws;
    u16* wq16  = hid16 + (size_t)S_LEN * HIDDEN;          // hid|wq|wk|wv|wo contiguous
    u16* wk16  = wq16 + (size_t)HIDDEN * HIDDEN;
    u16* wv16  = wk16 + (size_t)NKV * HD * HIDDEN;
    u16* wo16  = wv16 + (size_t)NKV * HD * HIDDEN;
    u16* qb    = wo16 + (size_t)HIDDEN * HIDDEN;
    u16* kb    = qb + (size_t)S_LEN * HIDDEN;
    u16* vt    = kb + (size_t)S_LEN * NKV * HD;
    u16* at    = vt + (size_t)S_LEN * NKV * HD;
    float2* tab = (float2*)(at + (size_t)S_LEN * HIDDEN);

    dim3 blk(256);

    // one fused convert: 12582912 float4s -> contiguous bf16 region at hid16
    cvt_all<<<dim3(12582912u / 256), blk, 0, stream>>>(hs, wq, wk, wv, wo, hid16);

    // fused QKV projection (V written transposed)
    gemm_qkv<<<dim3((HIDDEN + 2 * NKV * HD) / 128, S_LEN / 128), blk, 0, stream>>>(
        hid16, wq16, qb, kb, vt);

    DTab dt;
    for (int i = 0; i < 64; ++i) dt.f[i] = pow(500000.0, -(double)i / 64.0);
    const float qscale = 0.08838834764831845f * 1.4426950408889634f; // sm_scale*log2e
    rope_table<<<dim3(S_LEN * 64 / 256), blk, 0, stream>>>(pos, tab, dt);
    rope_apply<<<dim3((Q_ITEMS + S_LEN * NKV * 64) / 256), blk, 0, stream>>>(
        qb, kb, tab, qscale);

    attn_kernel<<<dim3(S_LEN / 128, NH), dim3(256), 0, stream>>>(qb, kb, vt, at);

    gemm_bt_f32<<<dim3(HIDDEN / 128, S_LEN / 128), blk, 0, stream>>>(
        at, wo16, out, HIDDEN, HIDDEN);
}

// Round 3
// 470.836 us; speedup vs baseline: 1.0944x; 1.0361x over previous
//
#include <hip/hip_runtime.h>
#include <stdint.h>
#include <cmath>

typedef unsigned short u16;
typedef unsigned int u32;
typedef __attribute__((ext_vector_type(8))) __bf16 bf16x8;
typedef __attribute__((ext_vector_type(4))) float f32x4;

#define HIDDEN 4096
#define NH 32
#define NKV 8
#define HD 128
#define S_LEN 2048

__device__ __forceinline__ u16 f2bf(float f) {
    u32 x = __float_as_uint(f);
    x += 0x7fff + ((x >> 16) & 1);   // RNE
    return (u16)(x >> 16);
}
__device__ __forceinline__ float bf2f(u16 u) {
    return __uint_as_float(((u32)u) << 16);
}
__device__ __forceinline__ float fexp2(float x) {
#if __has_builtin(__builtin_amdgcn_exp2f)
    return __builtin_amdgcn_exp2f(x);
#else
    return __expf(x * 0.6931471805599453f);
#endif
}
// compiler-native f32->bf16 (RNE; clang emits v_cvt_pk_bf16_f32 itself,
// with the operand order IT knows is right — unlike hand-written asm).
__device__ __forceinline__ u16 f2bf_native(float f) {
    union { __bf16 h; u16 u; } cv;
    cv.h = (__bf16)f;
    return cv.u;
}

// DPP rotate within 16-lane row (VALU pipe, not DS). row_ror:N = 0x120+N.
template <int N>
__device__ __forceinline__ float dpp_ror(float v) {
    int i = __builtin_amdgcn_update_dpp(0, __float_as_int(v),
                                        0x120 + N, 0xf, 0xf, true);
    return __int_as_float(i);
}
__device__ __forceinline__ float row_max16(float x) {
    x = fmaxf(x, dpp_ror<1>(x));
    x = fmaxf(x, dpp_ror<2>(x));
    x = fmaxf(x, dpp_ror<4>(x));
    x = fmaxf(x, dpp_ror<8>(x));
    return x;
}
__device__ __forceinline__ float row_sum16(float x) {
    x += dpp_ror<1>(x);
    x += dpp_ror<2>(x);
    x += dpp_ror<4>(x);
    x += dpp_ror<8>(x);
    return x;
}

typedef __attribute__((address_space(1))) const void gv_t;
typedef __attribute__((address_space(3))) void lv_t;
__device__ __forceinline__ void async16(const u16* g, u16* s) {
    __builtin_amdgcn_global_load_lds((gv_t*)g, (lv_t*)s, 16, 0, 0);
}

// ---------------- fused f32 -> bf16 convert (all 5 tensors, contiguous dst) ----------
#define F4_HS   2097152u
#define F4_WQ   4194304u
#define F4_WKV  1048576u
__global__ void cvt_all(const float* __restrict__ s0, const float* __restrict__ s1,
                        const float* __restrict__ s2, const float* __restrict__ s3,
                        const float* __restrict__ s4, u16* __restrict__ dst) {
    u32 i = blockIdx.x * 256 + threadIdx.x;   // < 12582912
    const float* src; u32 off;
    if (i < F4_HS)                              { src = s0; off = 0; }
    else if (i < F4_HS + F4_WQ)                 { src = s1; off = F4_HS; }
    else if (i < F4_HS + F4_WQ + F4_WKV)        { src = s2; off = F4_HS + F4_WQ; }
    else if (i < F4_HS + F4_WQ + 2 * F4_WKV)    { src = s3; off = F4_HS + F4_WQ + F4_WKV; }
    else                                        { src = s4; off = F4_HS + F4_WQ + 2 * F4_WKV; }
    float4 v = ((const float4*)src)[i - off];
    union { u16 u[4]; uint2 w; } pk;
    pk.u[0] = f2bf(v.x); pk.u[1] = f2bf(v.y);
    pk.u[2] = f2bf(v.z); pk.u[3] = f2bf(v.w);
    ((uint2*)dst)[i] = pk.w;
}

// ---------------- bf16 GEMM core: 128x128 tile, BK=64 ----------------
#define GEMM_PROLOGUE_AND_MAINLOOP(Aptr, Bptr, Kdim)                                   \
    __shared__ u16 sA[128 * 64];                                                       \
    __shared__ u16 sB[128 * 64];                                                       \
    const int tid = threadIdx.x;                                                       \
    const int w = tid >> 6, lane = tid & 63;                                           \
    const int l15 = lane & 15, quad = lane >> 4;                                       \
    const int m0 = blockIdx.y * 128, n0 = blockIdx.x * 128;                            \
    const int wm = w & 1, wn = w >> 1;                                                 \
    f32x4 acc[4][4];                                                                   \
    _Pragma("unroll") for (int mi = 0; mi < 4; ++mi)                                   \
    _Pragma("unroll") for (int ni = 0; ni < 4; ++ni)                                   \
    _Pragma("unroll") for (int r = 0; r < 4; ++r) acc[mi][ni][r] = 0.f;                \
    for (int kt = 0; kt < (Kdim); kt += 64) {                                          \
        _Pragma("unroll") for (int i = 0; i < 4; ++i) {                                \
            int c = (i * 4 + w) * 64 + lane;                                           \
            int r = c >> 3, sl = c & 7, g = sl ^ (r & 7);                              \
            async16((Aptr) + (size_t)(m0 + r) * (Kdim) + kt + g * 8, &sA[c * 8]);      \
        }                                                                              \
        _Pragma("unroll") for (int i = 0; i < 4; ++i) {                                \
            int c = (i * 4 + w) * 64 + lane;                                           \
            int r = c >> 3, sl = c & 7, g = sl ^ (r & 7);                              \
            async16((Bptr) + (size_t)(n0 + r) * (Kdim) + kt + g * 8, &sB[c * 8]);      \
        }                                                                              \
        __syncthreads();                                                               \
        _Pragma("unroll") for (int ks = 0; ks < 2; ++ks) {                             \
            bf16x8 af[4], bf[4];                                                       \
            _Pragma("unroll") for (int t = 0; t < 4; ++t) {                            \
                int row = wm * 64 + t * 16 + l15;                                      \
                int sl = (ks * 4 + quad) ^ (row & 7);                                  \
                af[t] = *(const bf16x8*)&sA[row * 64 + sl * 8];                        \
            }                                                                          \
            _Pragma("unroll") for (int t = 0; t < 4; ++t) {                            \
                int row = wn * 64 + t * 16 + l15;                                      \
                int sl = (ks * 4 + quad) ^ (row & 7);                                  \
                bf[t] = *(const bf16x8*)&sB[row * 64 + sl * 8];                        \
            }                                                                          \
            _Pragma("unroll") for (int mi = 0; mi < 4; ++mi)                           \
            _Pragma("unroll") for (int ni = 0; ni < 4; ++ni)                           \
                acc[mi][ni] = __builtin_amdgcn_mfma_f32_16x16x32_bf16(                 \
                    af[mi], bf[ni], acc[mi][ni], 0, 0, 0);                             \
        }                                                                              \
        __syncthreads();                                                               \
    }

// Generic: C[M,N] = A[M,K] * B[N,K]^T, f32 out (O-projection)
__global__ __launch_bounds__(256, 2) void gemm_bt_f32(
    const u16* __restrict__ A, const u16* __restrict__ B, float* __restrict__ C,
    int N, int K)
{
    GEMM_PROLOGUE_AND_MAINLOOP(A, B, K)
#pragma unroll
    for (int mi = 0; mi < 4; ++mi) {
        int row = m0 + wm * 64 + mi * 16 + quad * 4;
#pragma unroll
        for (int ni = 0; ni < 4; ++ni) {
            int col = n0 + wn * 64 + ni * 16 + l15;
#pragma unroll
            for (int r = 0; r < 4; ++r)
                C[(size_t)(row + r) * N + col] = acc[mi][ni][r];
        }
    }
}

// Fused QKV: A=[2048,4096] hs, B=[6144,4096] (wq|wk|wv rows), routed output.
__global__ __launch_bounds__(256, 2) void gemm_qkv(
    const u16* __restrict__ A, const u16* __restrict__ B,
    u16* __restrict__ qb, u16* __restrict__ kbuf, u16* __restrict__ vt)
{
    GEMM_PROLOGUE_AND_MAINLOOP(A, B, HIDDEN)
    if (n0 < 4096 + 1024) {   // q or k path: row-major bf16
        u16* outp; int ldo, cb;
        if (n0 < 4096) { outp = qb; ldo = HIDDEN; cb = n0; }
        else           { outp = kbuf; ldo = NKV * HD; cb = n0 - 4096; }
#pragma unroll
        for (int mi = 0; mi < 4; ++mi) {
            int row = m0 + wm * 64 + mi * 16 + quad * 4;
#pragma unroll
            for (int ni = 0; ni < 4; ++ni) {
                int col = cb + wn * 64 + ni * 16 + l15;
#pragma unroll
                for (int r = 0; r < 4; ++r)
                    outp[(size_t)(row + r) * ldo + col] = f2bf(acc[mi][ni][r]);
            }
        }
    } else {                  // v path: transposed vt[c][s]
        int cb = n0 - (4096 + 1024);
#pragma unroll
        for (int mi = 0; mi < 4; ++mi) {
            int row = m0 + wm * 64 + mi * 16 + quad * 4;
#pragma unroll
            for (int ni = 0; ni < 4; ++ni) {
                int c = cb + wn * 64 + ni * 16 + l15;
                union { u16 u[4]; uint2 v; } pk;
#pragma unroll
                for (int r = 0; r < 4; ++r) pk.u[r] = f2bf(acc[mi][ni][r]);
                *(uint2*)&vt[(size_t)c * S_LEN + row] = pk.v;
            }
        }
    }
}

// ---------------- RoPE: f64 table precompute + bf16 apply ----------------
struct DTab { double f[64]; };
__global__ void rope_table(const int* __restrict__ pos, float2* __restrict__ tab,
                           DTab dt) {
    int idx = blockIdx.x * 256 + threadIdx.x;   // < 2048*64
    int d = idx & 63, s = idx >> 6;
    double fr = (double)pos[s] * dt.f[d];
    double sd, cd;
    sincos(fr, &sd, &cd);
    tab[idx] = make_float2((float)cd, (float)sd);
}

#define Q_ITEMS (S_LEN * NH * 64)    // 4194304
__global__ void rope_apply(u16* __restrict__ qb, u16* __restrict__ kb,
                           const float2* __restrict__ tab, float qscale) {
    int idx = blockIdx.x * 256 + threadIdx.x;
    u16* buf; int logH; float osc;
    if (idx < Q_ITEMS) { buf = qb; logH = 5; osc = qscale; }
    else { idx -= Q_ITEMS; buf = kb; logH = 3; osc = 1.0f; }
    int d = idx & 63;
    int rest = idx >> 6;            // = s*H + h
    int s = rest >> logH;
    float2 cs = tab[s * 64 + d];
    float c = cs.x * osc, sn = cs.y * osc;
    u16* p = buf + (size_t)rest * HD + d;
    float x1 = bf2f(p[0]), x2 = bf2f(p[64]);
    p[0]  = f2bf(x1 * c - x2 * sn);
    p[64] = f2bf(x2 * c + x1 * sn);
}

// ---------------- flash attention ----------------
// v4: softmax VALU diet on top of v3.
//  - P->bf16 via compiler-native cast (v_cvt_pk_bf16_f32 emitted by clang;
//    ~1 op/2 values vs 5-op hand RNE). Same RNE rounding -> bit-identical.
//  - l_r kept as LANE-PARTIAL sums; the row_sum16 DPP reduction moved out of
//    the K-loop to the finalize (alpha rescale is row-uniform so scaling
//    partials is exact). Saves 32 DPP adds/tile.
// Geometry: q-tile 128 (4 waves), KBLK 64, 512 blocks -> 2 blocks/CU.
// Defer-rescale (T13) unchanged. Pipeline unchanged.
__global__ __launch_bounds__(256, 2) void attn_kernel(
    const u16* __restrict__ Q, const u16* __restrict__ Kb,
    const u16* __restrict__ Vt, u16* __restrict__ O)
{
    __shared__ u16 sK[64 * 128];                     // 16 KB
    __shared__ u16 sV[128 * 64];                     // 16 KB
    __shared__ __align__(16) u16 sP[4][8 * 264];     // 16.5 KB, per-wave private
    __shared__ float sAl[4][32];

    const int tid = threadIdx.x;
    const int w = tid >> 6, lane = tid & 63;
    const int l15 = lane & 15, quad = lane >> 4;
    const int h = blockIdx.y, q0 = blockIdx.x * 128;
    const int hk = h >> 2;
    u16* const sPw = sP[w];

    // Q frags (A-operand: m=lane&15, k=quad*8+j); Q pre-scaled by sm_scale*log2e
    bf16x8 qf[2][4];
#pragma unroll
    for (int mt = 0; mt < 2; ++mt)
#pragma unroll
        for (int ks = 0; ks < 4; ++ks)
            qf[mt][ks] = *(const bf16x8*)(Q + (size_t)(q0 + w * 32 + mt * 16 + l15) * HIDDEN
                                           + h * HD + ks * 32 + quad * 8);

    f32x4 oc[8][2];
#pragma unroll
    for (int dt = 0; dt < 8; ++dt)
#pragma unroll
        for (int nt = 0; nt < 2; ++nt)
#pragma unroll
            for (int r = 0; r < 4; ++r) oc[dt][nt][r] = 0.f;
    float m_r[2][4], l_r[2][4];
#pragma unroll
    for (int mt = 0; mt < 2; ++mt)
#pragma unroll
        for (int r = 0; r < 4; ++r) { m_r[mt][r] = -1e30f; l_r[mt][r] = 0.f; }

    // staging: 1024 chunks of 16B per tile, 256 threads x 4; XOR swizzle.
    // k0 is the ELEMENT offset (kbi * 64).
    auto stageK = [&](int k0) {
#pragma unroll
        for (int i = 0; i < 4; ++i) {
            int c = i * 256 + tid;
            int r = c >> 4, sl = c & 15, g = sl ^ (r & 15);
            async16(Kb + (size_t)(k0 + r) * (NKV * HD) + hk * HD + g * 8, &sK[c * 8]);
        }
    };
    auto stageV = [&](int k0) {
#pragma unroll
        for (int i = 0; i < 4; ++i) {
            int c = i * 256 + tid;
            int r = c >> 3, sl = c & 7, g = sl ^ (r & 7);
            async16(Vt + (size_t)(hk * HD + r) * S_LEN + k0 + g * 8, &sV[c * 8]);
        }
    };

    stageK(0);
    stageV(0);
    __syncthreads();

    for (int kbi = 0; kbi < 32; ++kbi) {
        // ---- S = Q K^T from sK ----
        f32x4 sa[2][4];
#pragma unroll
        for (int mt = 0; mt < 2; ++mt)
#pragma unroll
            for (int nt = 0; nt < 4; ++nt)
#pragma unroll
                for (int r = 0; r < 4; ++r) sa[mt][nt][r] = 0.f;
#pragma unroll
        for (int ks = 0; ks < 4; ++ks) {
            bf16x8 kf[4];
#pragma unroll
            for (int nt = 0; nt < 4; ++nt) {
                int row = nt * 16 + l15;
                int sl = (ks * 4 + quad) ^ (row & 15);
                kf[nt] = *(const bf16x8*)&sK[row * 128 + sl * 8];
            }
#pragma unroll
            for (int mt = 0; mt < 2; ++mt)
#pragma unroll
                for (int nt = 0; nt < 4; ++nt)
                    sa[mt][nt] = __builtin_amdgcn_mfma_f32_16x16x32_bf16(
                        qf[mt][ks], kf[nt], sa[mt][nt], 0, 0, 0);
        }

        // ---- online softmax (DPP max, exp2 domain, deferred rescale) ----
        float mxv[2][4];
        bool grow = false;
#pragma unroll
        for (int mt = 0; mt < 2; ++mt)
#pragma unroll
            for (int r = 0; r < 4; ++r) {
                float mx = fmaxf(fmaxf(sa[mt][0][r], sa[mt][1][r]),
                                 fmaxf(sa[mt][2][r], sa[mt][3][r]));
                mx = row_max16(mx);
                mxv[mt][r] = mx;
                grow = grow || (mx > m_r[mt][r] + 8.f);
            }
        const int dorescale = __any((int)grow);   // wave-uniform
        if (dorescale) {
#pragma unroll
            for (int mt = 0; mt < 2; ++mt)
#pragma unroll
                for (int r = 0; r < 4; ++r) {
                    float mnew = fmaxf(m_r[mt][r], mxv[mt][r]);
                    float alpha = fexp2(m_r[mt][r] - mnew);
                    m_r[mt][r] = mnew;
                    l_r[mt][r] *= alpha;     // lane-partial; uniform scale is exact
                    if (l15 == 0) sAl[w][mt * 16 + quad * 4 + r] = alpha;
                }
        }
#pragma unroll
        for (int mt = 0; mt < 2; ++mt)
#pragma unroll
            for (int r = 0; r < 4; ++r) {
                int ql = mt * 16 + quad * 4 + r;
                // chunk-major P: (q,k) at (k>>3)*264 + q*8 + (k&7); k = nt*16+l15
                u16* pb = sPw + (l15 >> 3) * 264 + ql * 8 + (l15 & 7);
                float mm = m_r[mt][r];
                float p0 = fexp2(sa[mt][0][r] - mm);
                float p1 = fexp2(sa[mt][1][r] - mm);
                float p2 = fexp2(sa[mt][2][r] - mm);
                float p3 = fexp2(sa[mt][3][r] - mm);
                pb[0 * 528] = f2bf_native(p0);
                pb[1 * 528] = f2bf_native(p1);
                pb[2 * 528] = f2bf_native(p2);
                pb[3 * 528] = f2bf_native(p3);
                l_r[mt][r] += (p0 + p1) + (p2 + p3);   // lane-partial sum
            }

        __syncthreads();                    // A: all sK reads done; prior stageV drained
        if (kbi < 31) stageK((kbi + 1) * 64);

        // ---- rescale O^T acc (wave-local), only when the max actually grew ----
        if (dorescale) {
            float al0 = sAl[w][l15], al1 = sAl[w][16 + l15];
#pragma unroll
            for (int dt = 0; dt < 8; ++dt)
#pragma unroll
                for (int r = 0; r < 4; ++r) { oc[dt][0][r] *= al0; oc[dt][1][r] *= al1; }
        }

        // ---- O^T += V^T P^T from sV, sPw ----
#pragma unroll
        for (int ks = 0; ks < 2; ++ks) {
            bf16x8 vf[8], pf[2];
#pragma unroll
            for (int dt = 0; dt < 8; ++dt) {
                int row = dt * 16 + l15;
                int sl = (ks * 4 + quad) ^ (row & 7);
                vf[dt] = *(const bf16x8*)&sV[row * 64 + sl * 8];
            }
#pragma unroll
            for (int nt = 0; nt < 2; ++nt)
                pf[nt] = *(const bf16x8*)&sPw[(ks * 4 + quad) * 264 + (nt * 16 + l15) * 8];
#pragma unroll
            for (int dt = 0; dt < 8; ++dt)
#pragma unroll
                for (int nt = 0; nt < 2; ++nt)
                    oc[dt][nt] = __builtin_amdgcn_mfma_f32_16x16x32_bf16(
                        vf[dt], pf[nt], oc[dt][nt], 0, 0, 0);
        }

        __syncthreads();                    // B: all sV reads done; stageK drained
        if (kbi < 31) stageV((kbi + 1) * 64);
    }

    // ---- finalize: row-reduce l (deferred), normalize, store O bf16 ----
#pragma unroll
    for (int mt = 0; mt < 2; ++mt)
#pragma unroll
        for (int r = 0; r < 4; ++r) {
            float ls = row_sum16(l_r[mt][r]);      // all 16 lanes get the sum
            if (l15 == 0) sAl[w][mt * 16 + quad * 4 + r] = ls;
        }
    __builtin_amdgcn_s_waitcnt(0);  // no-op safety: sAl is wave-private rows
    float il[2];
    il[0] = 1.f / sAl[w][l15];
    il[1] = 1.f / sAl[w][16 + l15];
#pragma unroll
    for (int nt = 0; nt < 2; ++nt)
#pragma unroll
        for (int dt = 0; dt < 8; ++dt) {
            union { u16 u[4]; uint2 v; } pk;
#pragma unroll
            for (int r = 0; r < 4; ++r) pk.u[r] = f2bf(oc[dt][nt][r] * il[nt]);
            *(uint2*)(O + (size_t)(q0 + w * 32 + nt * 16 + l15) * HIDDEN
                        + h * HD + dt * 16 + quad * 4) = pk.v;
        }
}

// ---------------- host ----------------
extern "C" void kernel_launch(void* const* d_in, const int* in_sizes, int n_in,
                              void* d_out, int out_size, void* d_ws, size_t ws_size,
                              hipStream_t stream) {
    const float* hs = (const float*)d_in[0];
    const int* pos  = (const int*)d_in[1];
    const float* wq = (const float*)d_in[2];
    const float* wk = (const float*)d_in[3];
    const float* wv = (const float*)d_in[4];
    const float* wo = (const float*)d_in[5];
    float* out = (float*)d_out;

    u16* ws    = (u16*)d_ws;
    u16* hid16 = ws;
    u16* wq16  = hid16 + (size_t)S_LEN * HIDDEN;          // hid|wq|wk|wv|wo contiguous
    u16* wk16  = wq16 + (size_t)HIDDEN * HIDDEN;
    u16* wv16  = wk16 + (size_t)NKV * HD * HIDDEN;
    u16* wo16  = wv16 + (size_t)NKV * HD * HIDDEN;
    u16* qb    = wo16 + (size_t)HIDDEN * HIDDEN;
    u16* kb    = qb + (size_t)S_LEN * HIDDEN;
    u16* vt    = kb + (size_t)S_LEN * NKV * HD;
    u16* at    = vt + (size_t)S_LEN * NKV * HD;
    float2* tab = (float2*)(at + (size_t)S_LEN * HIDDEN);

    dim3 blk(256);

    // one fused convert: 12582912 float4s -> contiguous bf16 region at hid16
    cvt_all<<<dim3(12582912u / 256), blk, 0, stream>>>(hs, wq, wk, wv, wo, hid16);

    // fused QKV projection (V written transposed)
    gemm_qkv<<<dim3((HIDDEN + 2 * NKV * HD) / 128, S_LEN / 128), blk, 0, stream>>>(
        hid16, wq16, qb, kb, vt);

    DTab dt;
    for (int i = 0; i < 64; ++i) dt.f[i] = pow(500000.0, -(double)i / 64.0);
    const float qscale = 0.08838834764831845f * 1.4426950408889634f; // sm_scale*log2e
    rope_table<<<dim3(S_LEN * 64 / 256), blk, 0, stream>>>(pos, tab, dt);
    rope_apply<<<dim3((Q_ITEMS + S_LEN * NKV * 64) / 256), blk, 0, stream>>>(
        qb, kb, tab, qscale);

    attn_kernel<<<dim3(S_LEN / 128, NH), dim3(256), 0, stream>>>(qb, kb, vt, at);

    gemm_bt_f32<<<dim3(HIDDEN / 128, S_LEN / 128), blk, 0, stream>>>(
        at, wo16, out, HIDDEN, HIDDEN);
}

// Round 6
// 465.694 us; speedup vs baseline: 1.1064x; 1.0110x over previous
//
#include <hip/hip_runtime.h>
#include <stdint.h>
#include <cmath>

typedef unsigned short u16;
typedef unsigned int u32;
typedef __attribute__((ext_vector_type(8))) __bf16 bf16x8;
typedef __attribute__((ext_vector_type(4))) float f32x4;

#define HIDDEN 4096
#define NH 32
#define NKV 8
#define HD 128
#define S_LEN 2048

__device__ __forceinline__ u16 f2bf(float f) {
    u32 x = __float_as_uint(f);
    x += 0x7fff + ((x >> 16) & 1);   // RNE
    return (u16)(x >> 16);
}
__device__ __forceinline__ float bf2f(u16 u) {
    return __uint_as_float(((u32)u) << 16);
}
__device__ __forceinline__ float fexp2(float x) {
#if __has_builtin(__builtin_amdgcn_exp2f)
    return __builtin_amdgcn_exp2f(x);
#else
    return __expf(x * 0.6931471805599453f);
#endif
}

typedef __attribute__((address_space(1))) const void gv_t;
typedef __attribute__((address_space(3))) void lv_t;
__device__ __forceinline__ void async16(const u16* g, u16* s) {
    __builtin_amdgcn_global_load_lds((gv_t*)g, (lv_t*)s, 16, 0, 0);
}

// ---------------- fused f32 -> bf16 convert (all 5 tensors, contiguous dst) ----------
#define F4_HS   2097152u
#define F4_WQ   4194304u
#define F4_WKV  1048576u
__global__ void cvt_all(const float* __restrict__ s0, const float* __restrict__ s1,
                        const float* __restrict__ s2, const float* __restrict__ s3,
                        const float* __restrict__ s4, u16* __restrict__ dst) {
    u32 i = blockIdx.x * 256 + threadIdx.x;   // < 12582912
    const float* src; u32 off;
    if (i < F4_HS)                              { src = s0; off = 0; }
    else if (i < F4_HS + F4_WQ)                 { src = s1; off = F4_HS; }
    else if (i < F4_HS + F4_WQ + F4_WKV)        { src = s2; off = F4_HS + F4_WQ; }
    else if (i < F4_HS + F4_WQ + 2 * F4_WKV)    { src = s3; off = F4_HS + F4_WQ + F4_WKV; }
    else                                        { src = s4; off = F4_HS + F4_WQ + 2 * F4_WKV; }
    float4 v = ((const float4*)src)[i - off];
    union { u16 u[4]; uint2 w; } pk;
    pk.u[0] = f2bf(v.x); pk.u[1] = f2bf(v.y);
    pk.u[2] = f2bf(v.z); pk.u[3] = f2bf(v.w);
    ((uint2*)dst)[i] = pk.w;
}

// ---------------- bf16 GEMM core: 128x128 tile, BK=64 ----------------
#define GEMM_PROLOGUE_AND_MAINLOOP(Aptr, Bptr, Kdim)                                   \
    __shared__ u16 sA[128 * 64];                                                       \
    __shared__ u16 sB[128 * 64];                                                       \
    const int tid = threadIdx.x;                                                       \
    const int w = tid >> 6, lane = tid & 63;                                           \
    const int l15 = lane & 15, quad = lane >> 4;                                       \
    const int m0 = blockIdx.y * 128, n0 = blockIdx.x * 128;                            \
    const int wm = w & 1, wn = w >> 1;                                                 \
    f32x4 acc[4][4];                                                                   \
    _Pragma("unroll") for (int mi = 0; mi < 4; ++mi)                                   \
    _Pragma("unroll") for (int ni = 0; ni < 4; ++ni)                                   \
    _Pragma("unroll") for (int r = 0; r < 4; ++r) acc[mi][ni][r] = 0.f;                \
    for (int kt = 0; kt < (Kdim); kt += 64) {                                          \
        _Pragma("unroll") for (int i = 0; i < 4; ++i) {                                \
            int c = (i * 4 + w) * 64 + lane;                                           \
            int r = c >> 3, sl = c & 7, g = sl ^ (r & 7);                              \
            async16((Aptr) + (size_t)(m0 + r) * (Kdim) + kt + g * 8, &sA[c * 8]);      \
        }                                                                              \
        _Pragma("unroll") for (int i = 0; i < 4; ++i) {                                \
            int c = (i * 4 + w) * 64 + lane;                                           \
            int r = c >> 3, sl = c & 7, g = sl ^ (r & 7);                              \
            async16((Bptr) + (size_t)(n0 + r) * (Kdim) + kt + g * 8, &sB[c * 8]);      \
        }                                                                              \
        __syncthreads();                                                               \
        _Pragma("unroll") for (int ks = 0; ks < 2; ++ks) {                             \
            bf16x8 af[4], bf[4];                                                       \
            _Pragma("unroll") for (int t = 0; t < 4; ++t) {                            \
                int row = wm * 64 + t * 16 + l15;                                      \
                int sl = (ks * 4 + quad) ^ (row & 7);                                  \
                af[t] = *(const bf16x8*)&sA[row * 64 + sl * 8];                        \
            }                                                                          \
            _Pragma("unroll") for (int t = 0; t < 4; ++t) {                            \
                int row = wn * 64 + t * 16 + l15;                                      \
                int sl = (ks * 4 + quad) ^ (row & 7);                                  \
                bf[t] = *(const bf16x8*)&sB[row * 64 + sl * 8];                        \
            }                                                                          \
            _Pragma("unroll") for (int mi = 0; mi < 4; ++mi)                           \
            _Pragma("unroll") for (int ni = 0; ni < 4; ++ni)                           \
                acc[mi][ni] = __builtin_amdgcn_mfma_f32_16x16x32_bf16(                 \
                    af[mi], bf[ni], acc[mi][ni], 0, 0, 0);                             \
        }                                                                              \
        __syncthreads();                                                               \
    }

// Generic: C[M,N] = A[M,K] * B[N,K]^T, f32 out (O-projection)
__global__ __launch_bounds__(256, 2) void gemm_bt_f32(
    const u16* __restrict__ A, const u16* __restrict__ B, float* __restrict__ C,
    int N, int K)
{
    GEMM_PROLOGUE_AND_MAINLOOP(A, B, K)
#pragma unroll
    for (int mi = 0; mi < 4; ++mi) {
        int row = m0 + wm * 64 + mi * 16 + quad * 4;
#pragma unroll
        for (int ni = 0; ni < 4; ++ni) {
            int col = n0 + wn * 64 + ni * 16 + l15;
#pragma unroll
            for (int r = 0; r < 4; ++r)
                C[(size_t)(row + r) * N + col] = acc[mi][ni][r];
        }
    }
}

// Fused QKV: A=[2048,4096] hs, B=[6144,4096] (wq|wk|wv rows), routed output.
__global__ __launch_bounds__(256, 2) void gemm_qkv(
    const u16* __restrict__ A, const u16* __restrict__ B,
    u16* __restrict__ qb, u16* __restrict__ kbuf, u16* __restrict__ vt)
{
    GEMM_PROLOGUE_AND_MAINLOOP(A, B, HIDDEN)
    if (n0 < 4096 + 1024) {   // q or k path: row-major bf16
        u16* outp; int ldo, cb;
        if (n0 < 4096) { outp = qb; ldo = HIDDEN; cb = n0; }
        else           { outp = kbuf; ldo = NKV * HD; cb = n0 - 4096; }
#pragma unroll
        for (int mi = 0; mi < 4; ++mi) {
            int row = m0 + wm * 64 + mi * 16 + quad * 4;
#pragma unroll
            for (int ni = 0; ni < 4; ++ni) {
                int col = cb + wn * 64 + ni * 16 + l15;
#pragma unroll
                for (int r = 0; r < 4; ++r)
                    outp[(size_t)(row + r) * ldo + col] = f2bf(acc[mi][ni][r]);
            }
        }
    } else {                  // v path: transposed vt[c][s]
        int cb = n0 - (4096 + 1024);
#pragma unroll
        for (int mi = 0; mi < 4; ++mi) {
            int row = m0 + wm * 64 + mi * 16 + quad * 4;
#pragma unroll
            for (int ni = 0; ni < 4; ++ni) {
                int c = cb + wn * 64 + ni * 16 + l15;
                union { u16 u[4]; uint2 v; } pk;
#pragma unroll
                for (int r = 0; r < 4; ++r) pk.u[r] = f2bf(acc[mi][ni][r]);
                *(uint2*)&vt[(size_t)c * S_LEN + row] = pk.v;
            }
        }
    }
}

// ---------------- RoPE: f64 table precompute + bf16 apply ----------------
struct DTab { double f[64]; };
__global__ void rope_table(const int* __restrict__ pos, float2* __restrict__ tab,
                           DTab dt) {
    int idx = blockIdx.x * 256 + threadIdx.x;   // < 2048*64
    int d = idx & 63, s = idx >> 6;
    double fr = (double)pos[s] * dt.f[d];
    double sd, cd;
    sincos(fr, &sd, &cd);
    tab[idx] = make_float2((float)cd, (float)sd);
}

#define Q_ITEMS (S_LEN * NH * 64)    // 4194304
__global__ void rope_apply(u16* __restrict__ qb, u16* __restrict__ kb,
                           const float2* __restrict__ tab, float qscale) {
    int idx = blockIdx.x * 256 + threadIdx.x;
    u16* buf; int logH; float osc;
    if (idx < Q_ITEMS) { buf = qb; logH = 5; osc = qscale; }
    else { idx -= Q_ITEMS; buf = kb; logH = 3; osc = 1.0f; }
    int d = idx & 63;
    int rest = idx >> 6;            // = s*H + h
    int s = rest >> logH;
    float2 cs = tab[s * 64 + d];
    float c = cs.x * osc, sn = cs.y * osc;
    u16* p = buf + (size_t)rest * HD + d;
    float x1 = bf2f(p[0]), x2 = bf2f(p[64]);
    p[0]  = f2bf(x1 * c - x2 * sn);
    p[64] = f2bf(x2 * c + x1 * sn);
}

// ---------------- flash attention ----------------
// v6: swapped QK^T (sa = mfma(kf, qf)) + k-permutation-invariant PV.
// P[q = mt*16+l15][k = ntk*16 + quad*4 + r] = sa[ntk][mt][r]  (this lane).
// PV contraction Sum_k V^T[d][k] P^T[k][q] is invariant under permuting k on
// BOTH operands. Pick sigma(ks*32+quad*8+j) = (2ks+(j>>2))*16 + quad*4 + (j&3):
//  - B-operand pf[ks][nt] elems 0-3 = sa[2ks][nt][0..3], 4-7 = sa[2ks+1][nt][0..3]
//    -> pure same-lane register assembly. NO bpermute, NO sP LDS, NO selects.
//  - A-operand vf elems: k = ks*32+quad*4+{0..3} and +16 -> two 8B LDS reads
//    (granules g and g^2 under the XOR swizzle; row vs row+8 = 2-way = free).
// One barrier/tile with double-buffered sK/sV (64 KB -> 2 blocks/CU); next-tile
// stages issued before compute, drained by the end-of-tile barrier.
// Defer-rescale (T13) kept. alpha/l per-lane (q = mt*16+l15) -> no sAl.
__global__ __launch_bounds__(256, 2) void attn_kernel(
    const u16* __restrict__ Q, const u16* __restrict__ Kb,
    const u16* __restrict__ Vt, u16* __restrict__ O)
{
    __shared__ u16 sK[2][64 * 128];                  // 2 x 16 KB
    __shared__ u16 sV[2][128 * 64];                  // 2 x 16 KB

    const int tid = threadIdx.x;
    const int w = tid >> 6, lane = tid & 63;
    const int l15 = lane & 15, quad = lane >> 4;
    const int h = blockIdx.y, q0 = blockIdx.x * 128;
    const int hk = h >> 2;

    // Q frags (B-operand: n=lane&15, k=quad*8+j); Q pre-scaled by sm_scale*log2e
    bf16x8 qf[2][4];
#pragma unroll
    for (int mt = 0; mt < 2; ++mt)
#pragma unroll
        for (int ks = 0; ks < 4; ++ks)
            qf[mt][ks] = *(const bf16x8*)(Q + (size_t)(q0 + w * 32 + mt * 16 + l15) * HIDDEN
                                           + h * HD + ks * 32 + quad * 8);

    f32x4 oc[8][2];
#pragma unroll
    for (int dt = 0; dt < 8; ++dt)
#pragma unroll
        for (int nt = 0; nt < 2; ++nt)
#pragma unroll
            for (int r = 0; r < 4; ++r) oc[dt][nt][r] = 0.f;
    float m_r[2], l_r[2];
#pragma unroll
    for (int mt = 0; mt < 2; ++mt) { m_r[mt] = -1e30f; l_r[mt] = 0.f; }

    // staging: 1024 chunks of 16B per tile, 256 threads x 4; XOR swizzle.
    auto stageK = [&](int k0, u16* dst) {
#pragma unroll
        for (int i = 0; i < 4; ++i) {
            int c = i * 256 + tid;
            int r = c >> 4, sl = c & 15, g = sl ^ (r & 15);
            async16(Kb + (size_t)(k0 + r) * (NKV * HD) + hk * HD + g * 8, &dst[c * 8]);
        }
    };
    auto stageV = [&](int k0, u16* dst) {
#pragma unroll
        for (int i = 0; i < 4; ++i) {
            int c = i * 256 + tid;
            int r = c >> 3, sl = c & 7, g = sl ^ (r & 7);
            async16(Vt + (size_t)(hk * HD + r) * S_LEN + k0 + g * 8, &dst[c * 8]);
        }
    };

    stageK(0, sK[0]);
    stageV(0, sV[0]);
    __syncthreads();

    int cur = 0;
    for (int kbi = 0; kbi < 32; ++kbi) {
        // issue next-tile stages into the other buffer; they fly under compute
        if (kbi < 31) {
            stageK((kbi + 1) * 64, sK[cur ^ 1]);
            stageV((kbi + 1) * 64, sV[cur ^ 1]);
        }
        const u16* sKc = sK[cur];
        const u16* sVc = sV[cur];

        // ---- S^T = K Q^T : sa[ntk][mt] col=q_local(l15), row=k_local(quad*4+r) ----
        f32x4 sa[4][2];
#pragma unroll
        for (int nt = 0; nt < 4; ++nt)
#pragma unroll
            for (int mt = 0; mt < 2; ++mt)
#pragma unroll
                for (int r = 0; r < 4; ++r) sa[nt][mt][r] = 0.f;
#pragma unroll
        for (int ks = 0; ks < 4; ++ks) {
            bf16x8 kf[4];
#pragma unroll
            for (int nt = 0; nt < 4; ++nt) {
                int row = nt * 16 + l15;
                int sl = (ks * 4 + quad) ^ (row & 15);
                kf[nt] = *(const bf16x8*)&sKc[row * 128 + sl * 8];
            }
#pragma unroll
            for (int nt = 0; nt < 4; ++nt)
#pragma unroll
                for (int mt = 0; mt < 2; ++mt)
                    sa[nt][mt] = __builtin_amdgcn_mfma_f32_16x16x32_bf16(
                        kf[nt], qf[mt][ks], sa[nt][mt], 0, 0, 0);
        }

        // ---- online softmax: per-lane row stats for q = mt*16 + l15 ----
        float mxv[2];
        bool grow = false;
#pragma unroll
        for (int mt = 0; mt < 2; ++mt) {
            float mx = sa[0][mt][0];
#pragma unroll
            for (int nt = 0; nt < 4; ++nt)
#pragma unroll
                for (int r = 0; r < 4; ++r)
                    if (nt || r) mx = fmaxf(mx, sa[nt][mt][r]);
            mx = fmaxf(mx, __shfl_xor(mx, 16));
            mx = fmaxf(mx, __shfl_xor(mx, 32));
            mxv[mt] = mx;
            grow = grow || (mx > m_r[mt] + 8.f);
        }
        const int dorescale = __any((int)grow);   // wave-uniform
        if (dorescale) {
            float al[2];
#pragma unroll
            for (int mt = 0; mt < 2; ++mt) {
                float mnew = fmaxf(m_r[mt], mxv[mt]);
                al[mt] = fexp2(m_r[mt] - mnew);
                m_r[mt] = mnew;
                l_r[mt] *= al[mt];
            }
#pragma unroll
            for (int dt = 0; dt < 8; ++dt)
#pragma unroll
                for (int r = 0; r < 4; ++r) { oc[dt][0][r] *= al[0]; oc[dt][1][r] *= al[1]; }
        }

        // ---- P = exp2(S - m) -> bf16, assembled per sigma (same lane, reg only) ----
        bf16x8 pf[2][2];   // [ks][ntq]
#pragma unroll
        for (int mt = 0; mt < 2; ++mt) {
            float mm = m_r[mt];
            float lsum = 0.f;
#pragma unroll
            for (int ntk = 0; ntk < 4; ++ntk) {
                float p0 = fexp2(sa[ntk][mt][0] - mm);
                float p1 = fexp2(sa[ntk][mt][1] - mm);
                float p2 = fexp2(sa[ntk][mt][2] - mm);
                float p3 = fexp2(sa[ntk][mt][3] - mm);
                lsum += (p0 + p1) + (p2 + p3);
                const int kx = ntk >> 1, e = (ntk & 1) * 4;
                pf[kx][mt][e + 0] = (__bf16)p0;
                pf[kx][mt][e + 1] = (__bf16)p1;
                pf[kx][mt][e + 2] = (__bf16)p2;
                pf[kx][mt][e + 3] = (__bf16)p3;
            }
            l_r[mt] += lsum;   // lane-partial; reduced across quads at finalize
        }

        // ---- O^T += V^T P^T, V read k-permuted by sigma (2x 8B per frag) ----
#pragma unroll
        for (int ks = 0; ks < 2; ++ks) {
#pragma unroll
            for (int dt = 0; dt < 8; ++dt) {
                int row = dt * 16 + l15;
                int g1 = (ks * 4 + (quad >> 1)) ^ (row & 7);
                int base = row * 64 + (quad & 1) * 4;
                union { uint2 u2[2]; bf16x8 v; } vfu;
                vfu.u2[0] = *(const uint2*)&sVc[base + g1 * 8];
                vfu.u2[1] = *(const uint2*)&sVc[base + (g1 ^ 2) * 8];
#pragma unroll
                for (int nt = 0; nt < 2; ++nt)
                    oc[dt][nt] = __builtin_amdgcn_mfma_f32_16x16x32_bf16(
                        vfu.v, pf[ks][nt], oc[dt][nt], 0, 0, 0);
            }
        }

        __syncthreads();    // all reads of cur done; next-tile stages drained
        cur ^= 1;
    }

    // ---- finalize: cross-quad l sum, normalize, store O bf16 ----
    float il[2];
#pragma unroll
    for (int mt = 0; mt < 2; ++mt) {
        float ls = l_r[mt];
        ls += __shfl_xor(ls, 16);
        ls += __shfl_xor(ls, 32);
        il[mt] = 1.f / ls;
    }
#pragma unroll
    for (int nt = 0; nt < 2; ++nt)
#pragma unroll
        for (int dt = 0; dt < 8; ++dt) {
            union { u16 u[4]; uint2 v; } pk;
#pragma unroll
            for (int r = 0; r < 4; ++r) pk.u[r] = f2bf(oc[dt][nt][r] * il[nt]);
            *(uint2*)(O + (size_t)(q0 + w * 32 + nt * 16 + l15) * HIDDEN
                        + h * HD + dt * 16 + quad * 4) = pk.v;
        }
}

// ---------------- host ----------------
extern "C" void kernel_launch(void* const* d_in, const int* in_sizes, int n_in,
                              void* d_out, int out_size, void* d_ws, size_t ws_size,
                              hipStream_t stream) {
    const float* hs = (const float*)d_in[0];
    const int* pos  = (const int*)d_in[1];
    const float* wq = (const float*)d_in[2];
    const float* wk = (const float*)d_in[3];
    const float* wv = (const float*)d_in[4];
    const float* wo = (const float*)d_in[5];
    float* out = (float*)d_out;

    u16* ws    = (u16*)d_ws;
    u16* hid16 = ws;
    u16* wq16  = hid16 + (size_t)S_LEN * HIDDEN;          // hid|wq|wk|wv|wo contiguous
    u16* wk16  = wq16 + (size_t)HIDDEN * HIDDEN;
    u16* wv16  = wk16 + (size_t)NKV * HD * HIDDEN;
    u16* wo16  = wv16 + (size_t)NKV * HD * HIDDEN;
    u16* qb    = wo16 + (size_t)HIDDEN * HIDDEN;
    u16* kb    = qb + (size_t)S_LEN * HIDDEN;
    u16* vt    = kb + (size_t)S_LEN * NKV * HD;
    u16* at    = vt + (size_t)S_LEN * NKV * HD;
    float2* tab = (float2*)(at + (size_t)S_LEN * HIDDEN);

    dim3 blk(256);

    // one fused convert: 12582912 float4s -> contiguous bf16 region at hid16
    cvt_all<<<dim3(12582912u / 256), blk, 0, stream>>>(hs, wq, wk, wv, wo, hid16);

    // fused QKV projection (V written transposed)
    gemm_qkv<<<dim3((HIDDEN + 2 * NKV * HD) / 128, S_LEN / 128), blk, 0, stream>>>(
        hid16, wq16, qb, kb, vt);

    DTab dt;
    for (int i = 0; i < 64; ++i) dt.f[i] = pow(500000.0, -(double)i / 64.0);
    const float qscale = 0.08838834764831845f * 1.4426950408889634f; // sm_scale*log2e
    rope_table<<<dim3(S_LEN * 64 / 256), blk, 0, stream>>>(pos, tab, dt);
    rope_apply<<<dim3((Q_ITEMS + S_LEN * NKV * 64) / 256), blk, 0, stream>>>(
        qb, kb, tab, qscale);

    attn_kernel<<<dim3(S_LEN / 128, NH), dim3(256), 0, stream>>>(qb, kb, vt, at);

    gemm_bt_f32<<<dim3(HIDDEN / 128, S_LEN / 128), blk, 0, stream>>>(
        at, wo16, out, HIDDEN, HIDDEN);
}

// Round 7
// 455.953 us; speedup vs baseline: 1.1301x; 1.0214x over previous
//
#include <hip/hip_runtime.h>
#include <stdint.h>
#include <cmath>

typedef unsigned short u16;
typedef unsigned int u32;
typedef __attribute__((ext_vector_type(8))) __bf16 bf16x8;
typedef __attribute__((ext_vector_type(4))) float f32x4;

#define HIDDEN 4096
#define NH 32
#define NKV 8
#define HD 128
#define S_LEN 2048

__device__ __forceinline__ u16 f2bf(float f) {
    u32 x = __float_as_uint(f);
    x += 0x7fff + ((x >> 16) & 1);   // RNE
    return (u16)(x >> 16);
}
__device__ __forceinline__ float bf2f(u16 u) {
    return __uint_as_float(((u32)u) << 16);
}
__device__ __forceinline__ float fexp2(float x) {
#if __has_builtin(__builtin_amdgcn_exp2f)
    return __builtin_amdgcn_exp2f(x);
#else
    return __expf(x * 0.6931471805599453f);
#endif
}

typedef __attribute__((address_space(1))) const void gv_t;
typedef __attribute__((address_space(3))) void lv_t;
__device__ __forceinline__ void async16(const u16* g, u16* s) {
    __builtin_amdgcn_global_load_lds((gv_t*)g, (lv_t*)s, 16, 0, 0);
}

// ---------------- fused f32 -> bf16 convert (all 5 tensors, contiguous dst) ----------
#define F4_HS   2097152u
#define F4_WQ   4194304u
#define F4_WKV  1048576u
__global__ void cvt_all(const float* __restrict__ s0, const float* __restrict__ s1,
                        const float* __restrict__ s2, const float* __restrict__ s3,
                        const float* __restrict__ s4, u16* __restrict__ dst) {
    u32 i = blockIdx.x * 256 + threadIdx.x;   // < 12582912
    const float* src; u32 off;
    if (i < F4_HS)                              { src = s0; off = 0; }
    else if (i < F4_HS + F4_WQ)                 { src = s1; off = F4_HS; }
    else if (i < F4_HS + F4_WQ + F4_WKV)        { src = s2; off = F4_HS + F4_WQ; }
    else if (i < F4_HS + F4_WQ + 2 * F4_WKV)    { src = s3; off = F4_HS + F4_WQ + F4_WKV; }
    else                                        { src = s4; off = F4_HS + F4_WQ + 2 * F4_WKV; }
    float4 v = ((const float4*)src)[i - off];
    union { u16 u[4]; uint2 w; } pk;
    pk.u[0] = f2bf(v.x); pk.u[1] = f2bf(v.y);
    pk.u[2] = f2bf(v.z); pk.u[3] = f2bf(v.w);
    ((uint2*)dst)[i] = pk.w;
}

// ---------------- bf16 GEMM core: 128x128 tile, BK=64 ----------------
// sMem: contiguous 32 KB; sA/sB halves; sT (=sMem) reusable 128x128 bf16 scratch
// after the main loop (which ends with __syncthreads).
#define GEMM_PROLOGUE_AND_MAINLOOP(Aptr, Bptr, Kdim)                                   \
    __shared__ u16 sMem[2][128 * 64];                                                  \
    u16* const sA = sMem[0];                                                           \
    u16* const sB = sMem[1];                                                           \
    const int tid = threadIdx.x;                                                       \
    const int w = tid >> 6, lane = tid & 63;                                           \
    const int l15 = lane & 15, quad = lane >> 4;                                       \
    const int m0 = blockIdx.y * 128, n0 = blockIdx.x * 128;                            \
    const int wm = w & 1, wn = w >> 1;                                                 \
    f32x4 acc[4][4];                                                                   \
    _Pragma("unroll") for (int mi = 0; mi < 4; ++mi)                                   \
    _Pragma("unroll") for (int ni = 0; ni < 4; ++ni)                                   \
    _Pragma("unroll") for (int r = 0; r < 4; ++r) acc[mi][ni][r] = 0.f;                \
    for (int kt = 0; kt < (Kdim); kt += 64) {                                          \
        _Pragma("unroll") for (int i = 0; i < 4; ++i) {                                \
            int c = (i * 4 + w) * 64 + lane;                                           \
            int r = c >> 3, sl = c & 7, g = sl ^ (r & 7);                              \
            async16((Aptr) + (size_t)(m0 + r) * (Kdim) + kt + g * 8, &sA[c * 8]);      \
        }                                                                              \
        _Pragma("unroll") for (int i = 0; i < 4; ++i) {                                \
            int c = (i * 4 + w) * 64 + lane;                                           \
            int r = c >> 3, sl = c & 7, g = sl ^ (r & 7);                              \
            async16((Bptr) + (size_t)(n0 + r) * (Kdim) + kt + g * 8, &sB[c * 8]);      \
        }                                                                              \
        __syncthreads();                                                               \
        _Pragma("unroll") for (int ks = 0; ks < 2; ++ks) {                             \
            bf16x8 af[4], bf[4];                                                       \
            _Pragma("unroll") for (int t = 0; t < 4; ++t) {                            \
                int row = wm * 64 + t * 16 + l15;                                      \
                int sl = (ks * 4 + quad) ^ (row & 7);                                  \
                af[t] = *(const bf16x8*)&sA[row * 64 + sl * 8];                        \
            }                                                                          \
            _Pragma("unroll") for (int t = 0; t < 4; ++t) {                            \
                int row = wn * 64 + t * 16 + l15;                                      \
                int sl = (ks * 4 + quad) ^ (row & 7);                                  \
                bf[t] = *(const bf16x8*)&sB[row * 64 + sl * 8];                        \
            }                                                                          \
            _Pragma("unroll") for (int mi = 0; mi < 4; ++mi)                           \
            _Pragma("unroll") for (int ni = 0; ni < 4; ++ni)                           \
                acc[mi][ni] = __builtin_amdgcn_mfma_f32_16x16x32_bf16(                 \
                    af[mi], bf[ni], acc[mi][ni], 0, 0, 0);                             \
        }                                                                              \
        __syncthreads();                                                               \
    }

// Generic: C[M,N] = A[M,K] * B[N,K]^T, f32 out (O-projection)
__global__ __launch_bounds__(256, 2) void gemm_bt_f32(
    const u16* __restrict__ A, const u16* __restrict__ B, float* __restrict__ C,
    int N, int K)
{
    GEMM_PROLOGUE_AND_MAINLOOP(A, B, K)
#pragma unroll
    for (int mi = 0; mi < 4; ++mi) {
        int row = m0 + wm * 64 + mi * 16 + quad * 4;
#pragma unroll
        for (int ni = 0; ni < 4; ++ni) {
            int col = n0 + wn * 64 + ni * 16 + l15;
#pragma unroll
            for (int r = 0; r < 4; ++r)
                C[(size_t)(row + r) * N + col] = acc[mi][ni][r];
        }
    }
}

// Fused QKV: A=[2048,4096] hs, B=[6144,4096] (wq|wk|wv rows), routed output.
// k path applies RoPE in-epilogue via sT LDS pair-exchange (d <-> d^64).
__global__ __launch_bounds__(256, 2) void gemm_qkv(
    const u16* __restrict__ A, const u16* __restrict__ B,
    u16* __restrict__ qb, u16* __restrict__ kbuf, u16* __restrict__ vt,
    const float2* __restrict__ tab)
{
    GEMM_PROLOGUE_AND_MAINLOOP(A, B, HIDDEN)
    if (n0 < 4096) {          // q path: raw projection, row-major bf16 (rope in attn)
#pragma unroll
        for (int mi = 0; mi < 4; ++mi) {
            int row = m0 + wm * 64 + mi * 16 + quad * 4;
#pragma unroll
            for (int ni = 0; ni < 4; ++ni) {
                int col = n0 + wn * 64 + ni * 16 + l15;
#pragma unroll
                for (int r = 0; r < 4; ++r)
                    qb[(size_t)(row + r) * HIDDEN + col] = f2bf(acc[mi][ni][r]);
            }
        }
    } else if (n0 < 4096 + 1024) {   // k path: fused RoPE via LDS pair-exchange
        u16* const sT = (u16*)sMem;  // 128x128 bf16 = 32 KB (main loop done)
        int cb = n0 - 4096;
#pragma unroll
        for (int mi = 0; mi < 4; ++mi)
#pragma unroll
            for (int ni = 0; ni < 4; ++ni) {
                int cl = wn * 64 + ni * 16 + l15;
#pragma unroll
                for (int r = 0; r < 4; ++r) {
                    int rl = wm * 64 + mi * 16 + quad * 4 + r;
                    sT[rl * 128 + cl] = f2bf(acc[mi][ni][r]);
                }
            }
        __syncthreads();
#pragma unroll
        for (int mi = 0; mi < 4; ++mi)
#pragma unroll
            for (int ni = 0; ni < 4; ++ni) {
                int cl = wn * 64 + ni * 16 + l15;   // = within-head d (cb mult of 128)
#pragma unroll
                for (int r = 0; r < 4; ++r) {
                    int rl = wm * 64 + mi * 16 + quad * 4 + r;
                    int srow = m0 + rl;
                    float x1 = bf2f(sT[rl * 128 + cl]);
                    float x2 = bf2f(sT[rl * 128 + (cl ^ 64)]);
                    float2 cs = tab[(size_t)srow * 64 + (cl & 63)];
                    float o = (cl < 64) ? (x1 * cs.x - x2 * cs.y)
                                        : (x1 * cs.x + x2 * cs.y);
                    kbuf[(size_t)srow * (NKV * HD) + cb + cl] = f2bf(o);
                }
            }
    } else {                  // v path: transposed vt[c][s]
        int cb = n0 - (4096 + 1024);
#pragma unroll
        for (int mi = 0; mi < 4; ++mi) {
            int row = m0 + wm * 64 + mi * 16 + quad * 4;
#pragma unroll
            for (int ni = 0; ni < 4; ++ni) {
                int c = cb + wn * 64 + ni * 16 + l15;
                union { u16 u[4]; uint2 v; } pk;
#pragma unroll
                for (int r = 0; r < 4; ++r) pk.u[r] = f2bf(acc[mi][ni][r]);
                *(uint2*)&vt[(size_t)c * S_LEN + row] = pk.v;
            }
        }
    }
}

// ---------------- RoPE cos/sin table: f64 precompute ----------------
struct DTab { double f[64]; };
__global__ void rope_table(const int* __restrict__ pos, float2* __restrict__ tab,
                           DTab dt) {
    int idx = blockIdx.x * 256 + threadIdx.x;   // < 2048*64
    int d = idx & 63, s = idx >> 6;
    double fr = (double)pos[s] * dt.f[d];
    double sd, cd;
    sincos(fr, &sd, &cd);
    tab[idx] = make_float2((float)cd, (float)sd);
}

// ---------------- flash attention ----------------
// v7 = v6 + fused Q-RoPE in the prologue (lane-local: each thread holds d and
// d^64 across its 4 k-slices; qscale folded into c/s). Core loop unchanged.
__global__ __launch_bounds__(256, 2) void attn_kernel(
    const u16* __restrict__ Q, const u16* __restrict__ Kb,
    const u16* __restrict__ Vt, u16* __restrict__ O,
    const float2* __restrict__ tab, float qscale)
{
    __shared__ u16 sK[2][64 * 128];                  // 2 x 16 KB
    __shared__ u16 sV[2][128 * 64];                  // 2 x 16 KB

    const int tid = threadIdx.x;
    const int w = tid >> 6, lane = tid & 63;
    const int l15 = lane & 15, quad = lane >> 4;
    const int h = blockIdx.y, q0 = blockIdx.x * 128;
    const int hk = h >> 2;

    // Q frags (B-operand: n=lane&15, k=quad*8+j), RoPE + sm_scale*log2e fused.
    // ks=0,1 hold d = ks*32+quad*8+j (<64); ks+2 holds d+64 (same lane).
    bf16x8 qf[2][4];
#pragma unroll
    for (int mt = 0; mt < 2; ++mt) {
        int srow = q0 + w * 32 + mt * 16 + l15;
        const u16* qrow = Q + (size_t)srow * HIDDEN + h * HD;
        bf16x8 raw[4];
#pragma unroll
        for (int ks = 0; ks < 4; ++ks)
            raw[ks] = *(const bf16x8*)(qrow + ks * 32 + quad * 8);
#pragma unroll
        for (int a = 0; a < 2; ++a) {
            const float2* tp = &tab[(size_t)srow * 64 + a * 32 + quad * 8];
#pragma unroll
            for (int j = 0; j < 8; ++j) {
                float c = tp[j].x * qscale, sn = tp[j].y * qscale;
                float x1 = (float)raw[a][j], x2 = (float)raw[a + 2][j];
                qf[mt][a][j]     = (__bf16)(x1 * c - x2 * sn);
                qf[mt][a + 2][j] = (__bf16)(x2 * c + x1 * sn);
            }
        }
    }

    f32x4 oc[8][2];
#pragma unroll
    for (int dt = 0; dt < 8; ++dt)
#pragma unroll
        for (int nt = 0; nt < 2; ++nt)
#pragma unroll
            for (int r = 0; r < 4; ++r) oc[dt][nt][r] = 0.f;
    float m_r[2], l_r[2];
#pragma unroll
    for (int mt = 0; mt < 2; ++mt) { m_r[mt] = -1e30f; l_r[mt] = 0.f; }

    // staging: 1024 chunks of 16B per tile, 256 threads x 4; XOR swizzle.
    auto stageK = [&](int k0, u16* dst) {
#pragma unroll
        for (int i = 0; i < 4; ++i) {
            int c = i * 256 + tid;
            int r = c >> 4, sl = c & 15, g = sl ^ (r & 15);
            async16(Kb + (size_t)(k0 + r) * (NKV * HD) + hk * HD + g * 8, &dst[c * 8]);
        }
    };
    auto stageV = [&](int k0, u16* dst) {
#pragma unroll
        for (int i = 0; i < 4; ++i) {
            int c = i * 256 + tid;
            int r = c >> 3, sl = c & 7, g = sl ^ (r & 7);
            async16(Vt + (size_t)(hk * HD + r) * S_LEN + k0 + g * 8, &dst[c * 8]);
        }
    };

    stageK(0, sK[0]);
    stageV(0, sV[0]);
    __syncthreads();

    int cur = 0;
    for (int kbi = 0; kbi < 32; ++kbi) {
        // issue next-tile stages into the other buffer; they fly under compute
        if (kbi < 31) {
            stageK((kbi + 1) * 64, sK[cur ^ 1]);
            stageV((kbi + 1) * 64, sV[cur ^ 1]);
        }
        const u16* sKc = sK[cur];
        const u16* sVc = sV[cur];

        // ---- S^T = K Q^T : sa[ntk][mt] col=q_local(l15), row=k_local(quad*4+r) ----
        f32x4 sa[4][2];
#pragma unroll
        for (int nt = 0; nt < 4; ++nt)
#pragma unroll
            for (int mt = 0; mt < 2; ++mt)
#pragma unroll
                for (int r = 0; r < 4; ++r) sa[nt][mt][r] = 0.f;
#pragma unroll
        for (int ks = 0; ks < 4; ++ks) {
            bf16x8 kf[4];
#pragma unroll
            for (int nt = 0; nt < 4; ++nt) {
                int row = nt * 16 + l15;
                int sl = (ks * 4 + quad) ^ (row & 15);
                kf[nt] = *(const bf16x8*)&sKc[row * 128 + sl * 8];
            }
#pragma unroll
            for (int nt = 0; nt < 4; ++nt)
#pragma unroll
                for (int mt = 0; mt < 2; ++mt)
                    sa[nt][mt] = __builtin_amdgcn_mfma_f32_16x16x32_bf16(
                        kf[nt], qf[mt][ks], sa[nt][mt], 0, 0, 0);
        }

        // ---- online softmax: per-lane row stats for q = mt*16 + l15 ----
        float mxv[2];
        bool grow = false;
#pragma unroll
        for (int mt = 0; mt < 2; ++mt) {
            float mx = sa[0][mt][0];
#pragma unroll
            for (int nt = 0; nt < 4; ++nt)
#pragma unroll
                for (int r = 0; r < 4; ++r)
                    if (nt || r) mx = fmaxf(mx, sa[nt][mt][r]);
            mx = fmaxf(mx, __shfl_xor(mx, 16));
            mx = fmaxf(mx, __shfl_xor(mx, 32));
            mxv[mt] = mx;
            grow = grow || (mx > m_r[mt] + 8.f);
        }
        const int dorescale = __any((int)grow);   // wave-uniform
        if (dorescale) {
            float al[2];
#pragma unroll
            for (int mt = 0; mt < 2; ++mt) {
                float mnew = fmaxf(m_r[mt], mxv[mt]);
                al[mt] = fexp2(m_r[mt] - mnew);
                m_r[mt] = mnew;
                l_r[mt] *= al[mt];
            }
#pragma unroll
            for (int dt = 0; dt < 8; ++dt)
#pragma unroll
                for (int r = 0; r < 4; ++r) { oc[dt][0][r] *= al[0]; oc[dt][1][r] *= al[1]; }
        }

        // ---- P = exp2(S - m) -> bf16, assembled per sigma (same lane, reg only) ----
        bf16x8 pf[2][2];   // [ks][ntq]
#pragma unroll
        for (int mt = 0; mt < 2; ++mt) {
            float mm = m_r[mt];
            float lsum = 0.f;
#pragma unroll
            for (int ntk = 0; ntk < 4; ++ntk) {
                float p0 = fexp2(sa[ntk][mt][0] - mm);
                float p1 = fexp2(sa[ntk][mt][1] - mm);
                float p2 = fexp2(sa[ntk][mt][2] - mm);
                float p3 = fexp2(sa[ntk][mt][3] - mm);
                lsum += (p0 + p1) + (p2 + p3);
                const int kx = ntk >> 1, e = (ntk & 1) * 4;
                pf[kx][mt][e + 0] = (__bf16)p0;
                pf[kx][mt][e + 1] = (__bf16)p1;
                pf[kx][mt][e + 2] = (__bf16)p2;
                pf[kx][mt][e + 3] = (__bf16)p3;
            }
            l_r[mt] += lsum;   // lane-partial; reduced across quads at finalize
        }

        // ---- O^T += V^T P^T, V read k-permuted by sigma (2x 8B per frag) ----
#pragma unroll
        for (int ks = 0; ks < 2; ++ks) {
#pragma unroll
            for (int dt = 0; dt < 8; ++dt) {
                int row = dt * 16 + l15;
                int g1 = (ks * 4 + (quad >> 1)) ^ (row & 7);
                int base = row * 64 + (quad & 1) * 4;
                union { uint2 u2[2]; bf16x8 v; } vfu;
                vfu.u2[0] = *(const uint2*)&sVc[base + g1 * 8];
                vfu.u2[1] = *(const uint2*)&sVc[base + (g1 ^ 2) * 8];
#pragma unroll
                for (int nt = 0; nt < 2; ++nt)
                    oc[dt][nt] = __builtin_amdgcn_mfma_f32_16x16x32_bf16(
                        vfu.v, pf[ks][nt], oc[dt][nt], 0, 0, 0);
            }
        }

        __syncthreads();    // all reads of cur done; next-tile stages drained
        cur ^= 1;
    }

    // ---- finalize: cross-quad l sum, normalize, store O bf16 ----
    float il[2];
#pragma unroll
    for (int mt = 0; mt < 2; ++mt) {
        float ls = l_r[mt];
        ls += __shfl_xor(ls, 16);
        ls += __shfl_xor(ls, 32);
        il[mt] = 1.f / ls;
    }
#pragma unroll
    for (int nt = 0; nt < 2; ++nt)
#pragma unroll
        for (int dt = 0; dt < 8; ++dt) {
            union { u16 u[4]; uint2 v; } pk;
#pragma unroll
            for (int r = 0; r < 4; ++r) pk.u[r] = f2bf(oc[dt][nt][r] * il[nt]);
            *(uint2*)(O + (size_t)(q0 + w * 32 + nt * 16 + l15) * HIDDEN
                        + h * HD + dt * 16 + quad * 4) = pk.v;
        }
}

// ---------------- host ----------------
extern "C" void kernel_launch(void* const* d_in, const int* in_sizes, int n_in,
                              void* d_out, int out_size, void* d_ws, size_t ws_size,
                              hipStream_t stream) {
    const float* hs = (const float*)d_in[0];
    const int* pos  = (const int*)d_in[1];
    const float* wq = (const float*)d_in[2];
    const float* wk = (const float*)d_in[3];
    const float* wv = (const float*)d_in[4];
    const float* wo = (const float*)d_in[5];
    float* out = (float*)d_out;

    u16* ws    = (u16*)d_ws;
    u16* hid16 = ws;
    u16* wq16  = hid16 + (size_t)S_LEN * HIDDEN;          // hid|wq|wk|wv|wo contiguous
    u16* wk16  = wq16 + (size_t)HIDDEN * HIDDEN;
    u16* wv16  = wk16 + (size_t)NKV * HD * HIDDEN;
    u16* wo16  = wv16 + (size_t)NKV * HD * HIDDEN;
    u16* qb    = wo16 + (size_t)HIDDEN * HIDDEN;
    u16* kb    = qb + (size_t)S_LEN * HIDDEN;
    u16* vt    = kb + (size_t)S_LEN * NKV * HD;
    u16* at    = vt + (size_t)S_LEN * NKV * HD;
    float2* tab = (float2*)(at + (size_t)S_LEN * HIDDEN);

    dim3 blk(256);

    // one fused convert: 12582912 float4s -> contiguous bf16 region at hid16
    cvt_all<<<dim3(12582912u / 256), blk, 0, stream>>>(hs, wq, wk, wv, wo, hid16);

    // RoPE table first (gemm_qkv k-path consumes it in-epilogue)
    DTab dt;
    for (int i = 0; i < 64; ++i) dt.f[i] = pow(500000.0, -(double)i / 64.0);
    rope_table<<<dim3(S_LEN * 64 / 256), blk, 0, stream>>>(pos, tab, dt);

    // fused QKV projection (V written transposed; K rope'd in epilogue)
    gemm_qkv<<<dim3((HIDDEN + 2 * NKV * HD) / 128, S_LEN / 128), blk, 0, stream>>>(
        hid16, wq16, qb, kb, vt, tab);

    const float qscale = 0.08838834764831845f * 1.4426950408889634f; // sm_scale*log2e
    attn_kernel<<<dim3(S_LEN / 128, NH), dim3(256), 0, stream>>>(
        qb, kb, vt, at, tab, qscale);

    gemm_bt_f32<<<dim3(HIDDEN / 128, S_LEN / 128), blk, 0, stream>>>(
        at, wo16, out, HIDDEN, HIDDEN);
}